// Round 5
// baseline (309.695 us; speedup 1.0000x reference)
//
#include <hip/hip_runtime.h>

typedef __attribute__((ext_vector_type(8))) short short8;
typedef __attribute__((ext_vector_type(4))) float f32x4;

constexpr int SEQ = 16384, BATCH = 8, DIN = 256, NQKV = 768;
constexpr float SCALE = 0.17677669529663687f; // 32^-0.5
constexpr float EPS = 1e-5f;

__device__ __forceinline__ unsigned short f2bf(float f){
  unsigned int u = __float_as_uint(f);
  u = u + 0x7fffu + ((u >> 16) & 1u);   // RNE
  return (unsigned short)(u >> 16);
}
__device__ __forceinline__ float bf2f(unsigned short h){
  return __uint_as_float(((unsigned int)h) << 16);
}
__device__ __forceinline__ void gload_lds16(const void* g, void* l){
  __builtin_amdgcn_global_load_lds(
    (const __attribute__((address_space(1))) unsigned int*)g,
    (__attribute__((address_space(3))) unsigned int*)l, 16, 0, 0);
}

// ---- K0: Wqkv [256 x 768] fp32 -> WT [768 x 256] bf16 (transposed) ----
__global__ void k_wt(const float* __restrict__ W, unsigned short* __restrict__ WT){
  int id = blockIdx.x * 256 + threadIdx.x;
  int k = id / NQKV, n = id % NQKV;
  WT[n * DIN + k] = f2bf(W[id]);
}

// ---- K1: qkv GEMM, m97 structure, fused per-n-tile epilogues ----
// grid 6144 = 1024 m-tiles x 6 n-tiles (n-fastest after XCD swizzle).
// 256 thr / 4 waves (2x2), tile 128x128, BK=64, LDS double-buffered 64 KB.
__global__ __launch_bounds__(256, 2) void k_gemm(const float* __restrict__ X,
                                                 const unsigned short* __restrict__ WT,
                                                 unsigned short* __restrict__ Q,
                                                 unsigned short* __restrict__ wT,
                                                 unsigned short* __restrict__ vT,
                                                 float* __restrict__ sumw){
  __shared__ unsigned short As[2][128 * 64];  // 16 KB each, swizzled byte^=((row&7)<<4)
  __shared__ unsigned short Bs[2][128 * 64];

  const int bid = blockIdx.x;
  const int wg = (bid & 7) * 768 + (bid >> 3);   // bijective XCD swizzle (6144%8==0)
  const int nt = wg % 6, mt = wg / 6;
  const size_t m0 = (size_t)mt * 128;
  const int n0 = nt * 128;
  const int b = mt >> 7;
  const int mloc = (mt & 127) * 128;
  const int tid = threadIdx.x, wave = tid >> 6, lane = tid & 63;
  const int wr = wave >> 1, wc = wave & 1, lg = lane >> 4, li = lane & 15;

  const int arow = tid >> 1, ah2 = tid & 1;       // thread: 64 B of A tile
  float4 pa[8];
  auto aIssue = [&](int ks){
    const float* src = X + (m0 + arow) * 256 + ks * 64 + ah2 * 32;
    #pragma unroll
    for (int q = 0; q < 8; q++) pa[q] = *reinterpret_cast<const float4*>(src + q * 4);
  };
  auto aWrite = [&](int buf){
    #pragma unroll
    for (int q = 0; q < 4; q++){
      float4 u = pa[2 * q], v = pa[2 * q + 1];
      short8 s;
      s[0] = f2bf(u.x); s[1] = f2bf(u.y); s[2] = f2bf(u.z); s[3] = f2bf(u.w);
      s[4] = f2bf(v.x); s[5] = f2bf(v.y); s[6] = f2bf(v.z); s[7] = f2bf(v.w);
      int L = arow * 128 + ah2 * 64 + q * 16;
      *reinterpret_cast<short8*>((char*)As[buf] + (L ^ ((arow & 7) << 4))) = s;
    }
  };
  auto stageB = [&](int buf, int ks){
    #pragma unroll
    for (int it = 0; it < 4; it++){
      int L = (it * 256 + tid) * 16;
      int G = L ^ (((L >> 7) & 7) << 4);          // pre-swizzled source (rule 21)
      gload_lds16((const char*)WT + (size_t)(n0 + (L >> 7)) * 512 + ks * 128 + (G & 127),
                  (char*)Bs[buf] + L);
    }
  };

  f32x4 acc[4][4];
  const f32x4 zf = {0.f, 0.f, 0.f, 0.f};
  #pragma unroll
  for (int i = 0; i < 4; i++)
    #pragma unroll
    for (int j = 0; j < 4; j++) acc[i][j] = zf;

  // prologue: stage K-step 0
  aIssue(0); stageB(0, 0); aWrite(0);
  __syncthreads();

  int cur = 0;
  #pragma unroll
  for (int ks = 0; ks < 4; ks++){
    if (ks < 3){ aIssue(ks + 1); stageB(cur ^ 1, ks + 1); }
    #pragma unroll
    for (int kk = 0; kk < 2; kk++){
      short8 a[4], bb[4];
      #pragma unroll
      for (int i = 0; i < 4; i++){
        int row = wr * 64 + i * 16 + li;
        int L = row * 128 + (kk * 32 + lg * 8) * 2;
        a[i] = *reinterpret_cast<const short8*>((const char*)As[cur] + (L ^ ((row & 7) << 4)));
      }
      #pragma unroll
      for (int j = 0; j < 4; j++){
        int n = wc * 64 + j * 16 + li;
        int L = n * 128 + (kk * 32 + lg * 8) * 2;
        bb[j] = *reinterpret_cast<const short8*>((const char*)Bs[cur] + (L ^ ((n & 7) << 4)));
      }
      #pragma unroll
      for (int i = 0; i < 4; i++)
        #pragma unroll
        for (int j = 0; j < 4; j++)
          acc[i][j] = __builtin_amdgcn_mfma_f32_16x16x32_bf16(a[i], bb[j], acc[i][j], 0, 0, 0);
    }
    if (ks < 3) aWrite(cur ^ 1);
    __syncthreads();
    cur ^= 1;
  }

  if (nt < 2){
    // q epilogue: fp32 softmax per row per 32-col head, *SCALE, store bf16
    #pragma unroll
    for (int i = 0; i < 4; i++)
      #pragma unroll
      for (int r = 0; r < 4; r++){
        float a0 = acc[i][0][r], a1 = acc[i][1][r];
        float b0 = acc[i][2][r], b1 = acc[i][3][r];
        float mA = fmaxf(a0, a1), mB = fmaxf(b0, b1);
        #pragma unroll
        for (int mm = 1; mm < 16; mm <<= 1){
          mA = fmaxf(mA, __shfl_xor(mA, mm)); mB = fmaxf(mB, __shfl_xor(mB, mm));
        }
        float e0 = __expf(a0 - mA), e1 = __expf(a1 - mA);
        float e2 = __expf(b0 - mB), e3 = __expf(b1 - mB);
        float sA = e0 + e1, sB = e2 + e3;
        #pragma unroll
        for (int mm = 1; mm < 16; mm <<= 1){
          sA += __shfl_xor(sA, mm); sB += __shfl_xor(sB, mm);
        }
        float iA = SCALE / sA, iB = SCALE / sB;
        int row = wr * 64 + i * 16 + lg * 4 + r;
        unsigned short* rp = Q + (m0 + row) * 256 + nt * 128 + wc * 64;
        rp[li]      = f2bf(e0 * iA);
        rp[16 + li] = f2bf(e1 * iA);
        rp[32 + li] = f2bf(e2 * iB);
        rp[48 + li] = f2bf(e3 * iB);
      }
  } else if (nt < 4){
    // k epilogue: w=exp(k), transposed store wT[b][hd][token], column-sum atomics
    float cs[4] = {0.f, 0.f, 0.f, 0.f};
    #pragma unroll
    for (int i = 0; i < 4; i++)
      #pragma unroll
      for (int j = 0; j < 4; j++){
        int gcol = (nt - 2) * 128 + wc * 64 + j * 16 + li;
        unsigned short h0 = f2bf(__expf(acc[i][j][0]));
        unsigned short h1 = f2bf(__expf(acc[i][j][1]));
        unsigned short h2 = f2bf(__expf(acc[i][j][2]));
        unsigned short h3 = f2bf(__expf(acc[i][j][3]));
        cs[j] += bf2f(h0) + bf2f(h1) + bf2f(h2) + bf2f(h3);
        ushort4 pk; pk.x = h0; pk.y = h1; pk.z = h2; pk.w = h3;
        *reinterpret_cast<ushort4*>(wT + (((size_t)(b * 256 + gcol)) << 14)
                                       + mloc + wr * 64 + i * 16 + lg * 4) = pk;
      }
    #pragma unroll
    for (int j = 0; j < 4; j++){
      cs[j] += __shfl_xor(cs[j], 16); cs[j] += __shfl_xor(cs[j], 32);
    }
    if (lane < 16){
      #pragma unroll
      for (int j = 0; j < 4; j++)
        atomicAdd(&sumw[b * 256 + (nt - 2) * 128 + wc * 64 + j * 16 + li], cs[j]);
    }
  } else {
    // v epilogue: transposed store vT[b][hd][token]
    #pragma unroll
    for (int i = 0; i < 4; i++)
      #pragma unroll
      for (int j = 0; j < 4; j++){
        int gcol = (nt - 4) * 128 + wc * 64 + j * 16 + li;
        ushort4 pk;
        pk.x = f2bf(acc[i][j][0]); pk.y = f2bf(acc[i][j][1]);
        pk.z = f2bf(acc[i][j][2]); pk.w = f2bf(acc[i][j][3]);
        *reinterpret_cast<ushort4*>(vT + (((size_t)(b * 256 + gcol)) << 14)
                                       + mloc + wr * 64 + i * 16 + lg * 4) = pk;
      }
  }
}

// ---- K2: ctx[b,h] = w^T @ v via MFMA; 512 blocks = 64 bh x 8 chunks ----
__global__ __launch_bounds__(256) void k_ctx(const unsigned short* __restrict__ wT,
                                             const unsigned short* __restrict__ vT,
                                             float* __restrict__ ctxp){
  const int bid = blockIdx.x;
  const int bh = bid >> 3, ch = bid & 7;
  const int b = bh >> 3, h = bh & 7;
  const int tid = threadIdx.x, wave = tid >> 6, lane = tid & 63;
  const int lg = lane >> 4, li = lane & 15;
  const int ntok0 = ch * 2048 + wave * 512;
  const unsigned short* wb = wT + (((size_t)(b * 256 + h * 32)) << 14);
  const unsigned short* vb = vT + (((size_t)(b * 256 + h * 32)) << 14);
  const f32x4 zf = {0.f, 0.f, 0.f, 0.f};
  f32x4 c[2][2] = {{zf, zf}, {zf, zf}};
  #pragma unroll 4
  for (int st = 0; st < 16; st++){
    int n = ntok0 + st * 32 + lg * 8;
    short8 a0 = *reinterpret_cast<const short8*>(wb + ((size_t)li << 14) + n);
    short8 a1 = *reinterpret_cast<const short8*>(wb + ((size_t)(16 + li) << 14) + n);
    short8 b0 = *reinterpret_cast<const short8*>(vb + ((size_t)li << 14) + n);
    short8 b1 = *reinterpret_cast<const short8*>(vb + ((size_t)(16 + li) << 14) + n);
    c[0][0] = __builtin_amdgcn_mfma_f32_16x16x32_bf16(a0, b0, c[0][0], 0, 0, 0);
    c[0][1] = __builtin_amdgcn_mfma_f32_16x16x32_bf16(a0, b1, c[0][1], 0, 0, 0);
    c[1][0] = __builtin_amdgcn_mfma_f32_16x16x32_bf16(a1, b0, c[1][0], 0, 0, 0);
    c[1][1] = __builtin_amdgcn_mfma_f32_16x16x32_bf16(a1, b1, c[1][1], 0, 0, 0);
  }
  float* cp = ctxp + ((size_t)bh * 32 + ch * 4 + wave) * 1024;
  #pragma unroll
  for (int dh = 0; dh < 2; dh++)
    #pragma unroll
    for (int eh = 0; eh < 2; eh++)
      #pragma unroll
      for (int rr = 0; rr < 4; rr++)
        cp[(dh * 16 + lg * 4 + rr) * 32 + eh * 16 + li] = c[dh][eh][rr];
}

// ---- K2b: reduce 32 ctx partials, /sumw, fold Wout -> MT[b][j][hd] bf16 ----
__global__ __launch_bounds__(256) void k_build_m(const float* __restrict__ ctxp,
                                                 const float* __restrict__ sumw,
                                                 const float* __restrict__ Wout,
                                                 unsigned short* __restrict__ MT){
  __shared__ float ctxs[32][33];
  __shared__ float swb[32];
  int b = blockIdx.x >> 3, h = blockIdx.x & 7;
  int bh = b * 8 + h;
  int t = threadIdx.x;
  int e = t & 31, dq = t >> 5;
  float a0 = 0.f, a1 = 0.f, a2 = 0.f, a3 = 0.f;
  #pragma unroll 4
  for (int p = 0; p < 32; p++){
    const float* cp = ctxp + ((size_t)bh * 32 + p) * 1024;
    a0 += cp[dq * 32 + e];         a1 += cp[(dq + 8) * 32 + e];
    a2 += cp[(dq + 16) * 32 + e];  a3 += cp[(dq + 24) * 32 + e];
  }
  if (t < 32) swb[t] = sumw[b * 256 + h * 32 + t];
  __syncthreads();
  ctxs[dq][e]      = a0 / swb[dq];
  ctxs[dq + 8][e]  = a1 / swb[dq + 8];
  ctxs[dq + 16][e] = a2 / swb[dq + 16];
  ctxs[dq + 24][e] = a3 / swb[dq + 24];
  __syncthreads();
  float s[32];
  #pragma unroll
  for (int d = 0; d < 32; d++) s[d] = 0.f;
  for (int ee = 0; ee < 32; ee++){
    float wv = Wout[(size_t)(h * 32 + ee) * 256 + t];
    #pragma unroll
    for (int d = 0; d < 32; d++) s[d] += ctxs[d][ee] * wv;
  }
  unsigned short* mp = MT + (size_t)b * 65536 + (size_t)t * 256 + h * 32;
  #pragma unroll
  for (int d8 = 0; d8 < 4; d8++){
    short8 pk;
    #pragma unroll
    for (int q = 0; q < 8; q++) pk[q] = (short)f2bf(s[d8 * 8 + q]);
    *reinterpret_cast<short8*>(mp + d8 * 8) = pk;
  }
}

// ---- K3: out = LN( qs @ MT^T ) * gamma ; 2048 blocks x 256 thr, 64 rows/block ----
__global__ __launch_bounds__(256, 4) void k_out(const unsigned short* __restrict__ Qm,
                                                const unsigned short* __restrict__ MT,
                                                const float* __restrict__ gamma,
                                                float* __restrict__ out){
  __shared__ unsigned short Bs[64 * 256];  // 32 KB swizzled
  const int blk = blockIdx.x;
  const int b = blk >> 8;
  const size_t m0 = (size_t)blk * 64;
  const int tid = threadIdx.x, wave = tid >> 6, lane = tid & 63;
  const int lg = lane >> 4, li = lane & 15;

  short8 afrag[8];
  {
    const unsigned short* qr = Qm + (m0 + wave * 16 + li) * 256 + lg * 8;
    #pragma unroll
    for (int ks = 0; ks < 8; ks++)
      afrag[ks] = *reinterpret_cast<const short8*>(qr + ks * 32);
  }
  const char* mtb = (const char*)MT + (size_t)b * 131072;
  f32x4 acc[4][4];
  const f32x4 zf = {0.f, 0.f, 0.f, 0.f};
  #pragma unroll
  for (int jb = 0; jb < 4; jb++)
    #pragma unroll
    for (int j = 0; j < 4; j++) acc[jb][j] = zf;

  #pragma unroll
  for (int jb = 0; jb < 4; jb++){
    if (jb) __syncthreads();
    #pragma unroll
    for (int rr = 0; rr < 8; rr++){
      int L = rr * 4096 + tid * 16;
      int G = L ^ (((L >> 9) & 7) << 4);   // pre-swizzled source (rule 21)
      gload_lds16(mtb + (size_t)jb * 32768 + G, (char*)Bs + L);
    }
    __syncthreads();
    #pragma unroll
    for (int ks = 0; ks < 8; ks++)
      #pragma unroll
      for (int j = 0; j < 4; j++){
        int n = j * 16 + li;
        int L = n * 512 + (ks * 32 + lg * 8) * 2;
        short8 bb = *reinterpret_cast<const short8*>((const char*)Bs + (L ^ ((n & 7) << 4)));
        acc[jb][j] = __builtin_amdgcn_mfma_f32_16x16x32_bf16(afrag[ks], bb, acc[jb][j], 0, 0, 0);
      }
  }

  float gam[16];
  #pragma unroll
  for (int jb = 0; jb < 4; jb++)
    #pragma unroll
    for (int j = 0; j < 4; j++) gam[jb * 4 + j] = gamma[jb * 64 + j * 16 + li];
  #pragma unroll
  for (int r = 0; r < 4; r++){
    float s = 0.f, qq = 0.f;
    #pragma unroll
    for (int jb = 0; jb < 4; jb++)
      #pragma unroll
      for (int j = 0; j < 4; j++){ float v = acc[jb][j][r]; s += v; qq += v * v; }
    #pragma unroll
    for (int mm = 1; mm < 16; mm <<= 1){ s += __shfl_xor(s, mm); qq += __shfl_xor(qq, mm); }
    float mu = s * (1.f / 256.f);
    float var = qq * (1.f / 256.f) - mu * mu;
    float inv = rsqrtf(var + EPS);
    float* op = out + (m0 + wave * 16 + lg * 4 + r) * 256;
    #pragma unroll
    for (int jb = 0; jb < 4; jb++)
      #pragma unroll
      for (int j = 0; j < 4; j++)
        op[jb * 64 + j * 16 + li] = (acc[jb][j][r] - mu) * inv * gam[jb * 4 + j];
  }
}

extern "C" void kernel_launch(void* const* d_in, const int* in_sizes, int n_in,
                              void* d_out, int out_size, void* d_ws, size_t ws_size,
                              hipStream_t stream){
  const float* x     = (const float*)d_in[0];
  const float* Wqkv  = (const float*)d_in[1];
  const float* Wout  = (const float*)d_in[2];
  const float* gamma = (const float*)d_in[3];
  float* out = (float*)d_out;

  char* ws = (char*)d_ws;
  size_t off = 0;
  unsigned short* Q   = (unsigned short*)(ws + off); off += (size_t)BATCH * SEQ * 256 * 2;   // 67 MB
  unsigned short* wTb = (unsigned short*)(ws + off); off += (size_t)BATCH * 256 * SEQ * 2;   // 67 MB
  unsigned short* vTb = (unsigned short*)(ws + off); off += (size_t)BATCH * 256 * SEQ * 2;   // 67 MB
  unsigned short* WT  = (unsigned short*)(ws + off); off += (size_t)NQKV * DIN * 2;
  float* sumw         = (float*)(ws + off);          off += (size_t)BATCH * 256 * 4;
  float* ctxp         = (float*)(ws + off);          off += (size_t)64 * 32 * 1024 * 4;      // 8.4 MB
  unsigned short* MT  = (unsigned short*)(ws + off); off += (size_t)BATCH * 65536 * 2;

  k_wt<<<(NQKV * DIN) / 256, 256, 0, stream>>>(Wqkv, WT);
  hipMemsetAsync(sumw, 0, (size_t)BATCH * 256 * 4, stream);
  k_gemm<<<6144, 256, 0, stream>>>(x, WT, Q, wTb, vTb, sumw);
  k_ctx<<<512, 256, 0, stream>>>(wTb, vTb, ctxp);
  k_build_m<<<64, 256, 0, stream>>>(ctxp, sumw, Wout, MT);
  k_out<<<2048, 256, 0, stream>>>(Q, MT, gamma, out);
}

// Round 6
// 229.248 us; speedup vs baseline: 1.3509x; 1.3509x over previous
//
#include <hip/hip_runtime.h>
#include <hip/hip_bf16.h>

typedef __attribute__((ext_vector_type(8))) short short8;
typedef __attribute__((ext_vector_type(4))) float f32x4;

constexpr int SEQ = 16384, BATCH = 8, DIN = 256, NQKV = 768;
constexpr float SCALE = 0.17677669529663687f; // 32^-0.5
constexpr float EPS = 1e-5f;

// native HW convert (RNE) — let the compiler emit v_cvt_*_bf16 instead of
// a 6-op bit-twiddle chain (guide m240: scalar cast path is good)
__device__ __forceinline__ unsigned short f2bf(float f){
  __hip_bfloat16 h = __float2bfloat16(f);
  unsigned short u; __builtin_memcpy(&u, &h, 2); return u;
}
__device__ __forceinline__ float bf2f(unsigned short h){
  return __uint_as_float(((unsigned int)h) << 16);
}
__device__ __forceinline__ void gload_lds16(const void* g, void* l){
  __builtin_amdgcn_global_load_lds(
    (const __attribute__((address_space(1))) unsigned int*)g,
    (__attribute__((address_space(3))) unsigned int*)l, 16, 0, 0);
}

// ---- K0: Wqkv [256 x 768] fp32 -> WT [768 x 256] bf16 (transposed) ----
__global__ void k_wt(const float* __restrict__ W, unsigned short* __restrict__ WT){
  int id = blockIdx.x * 256 + threadIdx.x;
  int k = id / NQKV, n = id % NQKV;
  WT[n * DIN + k] = f2bf(W[id]);
}

// ---- K1: qkv GEMM; A in regs (128 rows/block), B = 12 x 64-col panels,
// double-buffered 2x32KB swizzled LDS, 1 barrier/panel, fused epilogues,
// all outputs row-major coalesced. 1024 blocks x 256 thr. ----
__global__ __launch_bounds__(256, 2) void k_gemm(const float* __restrict__ X,
                                                 const unsigned short* __restrict__ WT,
                                                 unsigned short* __restrict__ Q,
                                                 unsigned short* __restrict__ Wb,
                                                 unsigned short* __restrict__ Vb,
                                                 float* __restrict__ sumwp){
  __shared__ unsigned short Bs[2][64 * 256];   // 32 KB each, swizzle byte^=((row&7)<<4)
  __shared__ float sumLds[256];
  const int blk = blockIdx.x;
  const size_t m0 = (size_t)blk * 128;
  const int tid = threadIdx.x, wave = tid >> 6, lane = tid & 63;
  const int lg = lane >> 4, li = lane & 15;
  sumLds[tid] = 0.f;

  auto stageB = [&](int buf, int n0){
    #pragma unroll
    for (int it = 0; it < 8; it++){
      int L = (it * 256 + tid) * 16;
      int G = L ^ (((L >> 9) & 7) << 4);       // pre-swizzled source (rule 21)
      gload_lds16((const char*)WT + (size_t)(n0 + (L >> 9)) * 512 + (G & 511),
                  (char*)Bs[buf] + L);
    }
  };

  stageB(0, 0);
  // A fragments: 32 rows/wave, full K=256, fp32 -> bf16 native cvt (32 VGPR)
  short8 afrag[2][8];
  #pragma unroll
  for (int rt = 0; rt < 2; rt++){
    const float* xr = X + (m0 + wave * 32 + rt * 16 + li) * 256 + lg * 8;
    #pragma unroll
    for (int ks = 0; ks < 8; ks++){
      float4 f0 = *reinterpret_cast<const float4*>(xr + ks * 32);
      float4 f1 = *reinterpret_cast<const float4*>(xr + ks * 32 + 4);
      short8 a;
      a[0] = f2bf(f0.x); a[1] = f2bf(f0.y); a[2] = f2bf(f0.z); a[3] = f2bf(f0.w);
      a[4] = f2bf(f1.x); a[5] = f2bf(f1.y); a[6] = f2bf(f1.z); a[7] = f2bf(f1.w);
      afrag[rt][ks] = a;
    }
  }
  __syncthreads();

  const f32x4 zf = {0.f, 0.f, 0.f, 0.f};
  int buf = 0;
  #pragma unroll 1
  for (int p = 0; p < 12; ++p){
    if (p < 11) stageB(buf ^ 1, (p + 1) * 64);
    f32x4 acc[2][4];
    #pragma unroll
    for (int rt = 0; rt < 2; rt++)
      #pragma unroll
      for (int j = 0; j < 4; j++) acc[rt][j] = zf;
    #pragma unroll
    for (int ks = 0; ks < 8; ks++)
      #pragma unroll
      for (int j = 0; j < 4; j++){
        int nl = j * 16 + li;
        int L = nl * 512 + (ks * 32 + lg * 8) * 2;
        short8 bb = *reinterpret_cast<const short8*>((const char*)Bs[buf] + (L ^ ((nl & 7) << 4)));
        acc[0][j] = __builtin_amdgcn_mfma_f32_16x16x32_bf16(afrag[0][ks], bb, acc[0][j], 0, 0, 0);
        acc[1][j] = __builtin_amdgcn_mfma_f32_16x16x32_bf16(afrag[1][ks], bb, acc[1][j], 0, 0, 0);
      }
    // fused epilogue
    if (p < 4){
      // q panel: fp32 softmax per row per 32-col head, *SCALE
      #pragma unroll
      for (int rt = 0; rt < 2; rt++)
        #pragma unroll
        for (int rr = 0; rr < 4; rr++){
          float a0 = acc[rt][0][rr], a1 = acc[rt][1][rr];
          float b0 = acc[rt][2][rr], b1 = acc[rt][3][rr];
          float mA = fmaxf(a0, a1), mB = fmaxf(b0, b1);
          #pragma unroll
          for (int mm = 1; mm < 16; mm <<= 1){
            mA = fmaxf(mA, __shfl_xor(mA, mm)); mB = fmaxf(mB, __shfl_xor(mB, mm));
          }
          float e0 = __expf(a0 - mA), e1 = __expf(a1 - mA);
          float e2 = __expf(b0 - mB), e3 = __expf(b1 - mB);
          float sA = e0 + e1, sB = e2 + e3;
          #pragma unroll
          for (int mm = 1; mm < 16; mm <<= 1){
            sA += __shfl_xor(sA, mm); sB += __shfl_xor(sB, mm);
          }
          float iA = SCALE / sA, iB = SCALE / sB;
          unsigned short* rp = Q + (m0 + wave * 32 + rt * 16 + lg * 4 + rr) * 256 + p * 64;
          rp[li]      = f2bf(e0 * iA);
          rp[16 + li] = f2bf(e1 * iA);
          rp[32 + li] = f2bf(e2 * iB);
          rp[48 + li] = f2bf(e3 * iB);
        }
    } else if (p < 8){
      // k panel: w = exp(k) (k ~ N(0,1), safe), store bf16 + column sums
      int ph = p - 4;
      #pragma unroll
      for (int j = 0; j < 4; j++){
        float cs = 0.f;
        #pragma unroll
        for (int rt = 0; rt < 2; rt++)
          #pragma unroll
          for (int rr = 0; rr < 4; rr++){
            unsigned short hw = f2bf(__expf(acc[rt][j][rr]));
            cs += bf2f(hw);   // sum the rounded value (matches k_build_m division)
            Wb[(m0 + wave * 32 + rt * 16 + lg * 4 + rr) * 256 + ph * 64 + j * 16 + li] = hw;
          }
        cs += __shfl_xor(cs, 16); cs += __shfl_xor(cs, 32);
        if (lane < 16) atomicAdd(&sumLds[ph * 64 + j * 16 + li], cs);
      }
    } else {
      int pv = p - 8;
      #pragma unroll
      for (int j = 0; j < 4; j++)
        #pragma unroll
        for (int rt = 0; rt < 2; rt++)
          #pragma unroll
          for (int rr = 0; rr < 4; rr++)
            Vb[(m0 + wave * 32 + rt * 16 + lg * 4 + rr) * 256 + pv * 64 + j * 16 + li]
              = f2bf(acc[rt][j][rr]);
    }
    __syncthreads();
    buf ^= 1;
  }
  sumwp[(size_t)blk * 256 + tid] = sumLds[tid];
}

// ---- K2: ctx[b,h] = w^T @ v via LDS-transpose + MFMA.
// 512 blocks = 64 bh x 8 chunks of 2048 tokens; per-wave fp32 partials. ----
__global__ __launch_bounds__(256, 2) void k_ctx(const unsigned short* __restrict__ Wb,
                                                const unsigned short* __restrict__ Vb,
                                                float* __restrict__ ctxp){
  __shared__ unsigned short tw[32 * 528];   // [col][token], stride 528 (16B-aligned rows)
  __shared__ unsigned short tv[32 * 528];
  const int bid = blockIdx.x;
  const int bh = bid >> 3, ch = bid & 7;
  const int b = bh >> 3, h = bh & 7;
  const int tid = threadIdx.x, wave = tid >> 6, lane = tid & 63;
  const int lg = lane >> 4, li = lane & 15;
  const f32x4 zf = {0.f, 0.f, 0.f, 0.f};
  f32x4 c[2][2] = {{zf, zf}, {zf, zf}};
  const size_t base = ((size_t)b * SEQ + ch * 2048) * 256 + h * 32;

  #pragma unroll 1
  for (int it = 0; it < 4; it++){
    if (it) __syncthreads();
    #pragma unroll
    for (int s = 0; s < 4; s++){
      int tl = s * 128 + (tid >> 1);
      int c0 = (tid & 1) * 16;
      const unsigned short* sw = Wb + base + (size_t)(it * 512 + tl) * 256 + c0;
      short8 u0 = *reinterpret_cast<const short8*>(sw);
      short8 u1 = *reinterpret_cast<const short8*>(sw + 8);
      #pragma unroll
      for (int q = 0; q < 8; q++) tw[(c0 + q) * 528 + tl] = u0[q];
      #pragma unroll
      for (int q = 0; q < 8; q++) tw[(c0 + 8 + q) * 528 + tl] = u1[q];
      const unsigned short* sv = Vb + base + (size_t)(it * 512 + tl) * 256 + c0;
      short8 v0 = *reinterpret_cast<const short8*>(sv);
      short8 v1 = *reinterpret_cast<const short8*>(sv + 8);
      #pragma unroll
      for (int q = 0; q < 8; q++) tv[(c0 + q) * 528 + tl] = v0[q];
      #pragma unroll
      for (int q = 0; q < 8; q++) tv[(c0 + 8 + q) * 528 + tl] = v1[q];
    }
    __syncthreads();
    const int t0 = wave * 128;
    #pragma unroll
    for (int ks = 0; ks < 4; ks++){
      int o = t0 + ks * 32 + lg * 8;
      short8 a0 = *reinterpret_cast<const short8*>(&tw[li * 528 + o]);
      short8 a1 = *reinterpret_cast<const short8*>(&tw[(16 + li) * 528 + o]);
      short8 b0 = *reinterpret_cast<const short8*>(&tv[li * 528 + o]);
      short8 b1 = *reinterpret_cast<const short8*>(&tv[(16 + li) * 528 + o]);
      c[0][0] = __builtin_amdgcn_mfma_f32_16x16x32_bf16(a0, b0, c[0][0], 0, 0, 0);
      c[0][1] = __builtin_amdgcn_mfma_f32_16x16x32_bf16(a0, b1, c[0][1], 0, 0, 0);
      c[1][0] = __builtin_amdgcn_mfma_f32_16x16x32_bf16(a1, b0, c[1][0], 0, 0, 0);
      c[1][1] = __builtin_amdgcn_mfma_f32_16x16x32_bf16(a1, b1, c[1][1], 0, 0, 0);
    }
  }
  float* cp = ctxp + (((size_t)bh * 8 + ch) * 4 + wave) * 1024;   // = bh*32 + (ch*4+wave)
  #pragma unroll
  for (int dh = 0; dh < 2; dh++)
    #pragma unroll
    for (int eh = 0; eh < 2; eh++)
      #pragma unroll
      for (int rr = 0; rr < 4; rr++)
        cp[(dh * 16 + lg * 4 + rr) * 32 + eh * 16 + li] = c[dh][eh][rr];
}

// ---- K2b: reduce 32 ctx partials, /sumw, fold Wout -> MT[b][j][hd] bf16 ----
__global__ __launch_bounds__(256) void k_build_m(const float* __restrict__ ctxp,
                                                 const float* __restrict__ sumwp,
                                                 const float* __restrict__ Wout,
                                                 unsigned short* __restrict__ MT){
  __shared__ float ctxs[32][33];
  __shared__ float swb[32];
  int b = blockIdx.x >> 3, h = blockIdx.x & 7;
  int bh = b * 8 + h;
  int t = threadIdx.x;
  int e = t & 31, dq = t >> 5;
  float a0 = 0.f, a1 = 0.f, a2 = 0.f, a3 = 0.f;
  #pragma unroll 4
  for (int p = 0; p < 32; p++){
    const float* cp = ctxp + ((size_t)bh * 32 + p) * 1024;
    a0 += cp[dq * 32 + e];         a1 += cp[(dq + 8) * 32 + e];
    a2 += cp[(dq + 16) * 32 + e];  a3 += cp[(dq + 24) * 32 + e];
  }
  if (t < 32){
    float sw = 0.f;
    #pragma unroll 8
    for (int mb = 0; mb < 128; mb++)
      sw += sumwp[(size_t)(b * 128 + mb) * 256 + h * 32 + t];
    swb[t] = sw;
  }
  __syncthreads();
  ctxs[dq][e]      = a0 / swb[dq];
  ctxs[dq + 8][e]  = a1 / swb[dq + 8];
  ctxs[dq + 16][e] = a2 / swb[dq + 16];
  ctxs[dq + 24][e] = a3 / swb[dq + 24];
  __syncthreads();
  float s[32];
  #pragma unroll
  for (int d = 0; d < 32; d++) s[d] = 0.f;
  for (int ee = 0; ee < 32; ee++){
    float wv = Wout[(size_t)(h * 32 + ee) * 256 + t];
    #pragma unroll
    for (int d = 0; d < 32; d++) s[d] += ctxs[d][ee] * wv;
  }
  unsigned short* mp = MT + (size_t)b * 65536 + (size_t)t * 256 + h * 32;
  #pragma unroll
  for (int d8 = 0; d8 < 4; d8++){
    short8 pk;
    #pragma unroll
    for (int q = 0; q < 8; q++) pk[q] = (short)f2bf(s[d8 * 8 + q]);
    *reinterpret_cast<short8*>(mp + d8 * 8) = pk;
  }
}

// ---- K3: out = LN( qs @ MT^T ) * gamma ; 2048 blocks x 256 thr, 64 rows/block ----
__global__ __launch_bounds__(256, 4) void k_out(const unsigned short* __restrict__ Qm,
                                                const unsigned short* __restrict__ MT,
                                                const float* __restrict__ gamma,
                                                float* __restrict__ out){
  __shared__ unsigned short Bs[64 * 256];  // 32 KB swizzled
  const int blk = blockIdx.x;
  const int b = blk >> 8;
  const size_t m0 = (size_t)blk * 64;
  const int tid = threadIdx.x, wave = tid >> 6, lane = tid & 63;
  const int lg = lane >> 4, li = lane & 15;

  short8 afrag[8];
  {
    const unsigned short* qr = Qm + (m0 + wave * 16 + li) * 256 + lg * 8;
    #pragma unroll
    for (int ks = 0; ks < 8; ks++)
      afrag[ks] = *reinterpret_cast<const short8*>(qr + ks * 32);
  }
  const char* mtb = (const char*)MT + (size_t)b * 131072;
  f32x4 acc[4][4];
  const f32x4 zf = {0.f, 0.f, 0.f, 0.f};
  #pragma unroll
  for (int jb = 0; jb < 4; jb++)
    #pragma unroll
    for (int j = 0; j < 4; j++) acc[jb][j] = zf;

  #pragma unroll
  for (int jb = 0; jb < 4; jb++){
    if (jb) __syncthreads();
    #pragma unroll
    for (int rr = 0; rr < 8; rr++){
      int L = rr * 4096 + tid * 16;
      int G = L ^ (((L >> 9) & 7) << 4);   // pre-swizzled source (rule 21)
      gload_lds16(mtb + (size_t)jb * 32768 + G, (char*)Bs + L);
    }
    __syncthreads();
    #pragma unroll
    for (int ks = 0; ks < 8; ks++)
      #pragma unroll
      for (int j = 0; j < 4; j++){
        int n = j * 16 + li;
        int L = n * 512 + (ks * 32 + lg * 8) * 2;
        short8 bb = *reinterpret_cast<const short8*>((const char*)Bs + (L ^ ((n & 7) << 4)));
        acc[jb][j] = __builtin_amdgcn_mfma_f32_16x16x32_bf16(afrag[ks], bb, acc[jb][j], 0, 0, 0);
      }
  }

  float gam[16];
  #pragma unroll
  for (int jb = 0; jb < 4; jb++)
    #pragma unroll
    for (int j = 0; j < 4; j++) gam[jb * 4 + j] = gamma[jb * 64 + j * 16 + li];
  #pragma unroll
  for (int r = 0; r < 4; r++){
    float s = 0.f, qq = 0.f;
    #pragma unroll
    for (int jb = 0; jb < 4; jb++)
      #pragma unroll
      for (int j = 0; j < 4; j++){ float v = acc[jb][j][r]; s += v; qq += v * v; }
    #pragma unroll
    for (int mm = 1; mm < 16; mm <<= 1){ s += __shfl_xor(s, mm); qq += __shfl_xor(qq, mm); }
    float mu = s * (1.f / 256.f);
    float var = qq * (1.f / 256.f) - mu * mu;
    float inv = rsqrtf(var + EPS);
    float* op = out + (m0 + wave * 16 + lg * 4 + r) * 256;
    #pragma unroll
    for (int jb = 0; jb < 4; jb++)
      #pragma unroll
      for (int j = 0; j < 4; j++)
        op[jb * 64 + j * 16 + li] = (acc[jb][j][r] - mu) * inv * gam[jb * 4 + j];
  }
}

extern "C" void kernel_launch(void* const* d_in, const int* in_sizes, int n_in,
                              void* d_out, int out_size, void* d_ws, size_t ws_size,
                              hipStream_t stream){
  const float* x     = (const float*)d_in[0];
  const float* Wqkv  = (const float*)d_in[1];
  const float* Wout  = (const float*)d_in[2];
  const float* gamma = (const float*)d_in[3];
  float* out = (float*)d_out;

  char* ws = (char*)d_ws;
  size_t off = 0;
  unsigned short* Q   = (unsigned short*)(ws + off); off += (size_t)BATCH * SEQ * 256 * 2;   // 67 MB
  unsigned short* Wb  = (unsigned short*)(ws + off); off += (size_t)BATCH * SEQ * 256 * 2;   // 67 MB
  unsigned short* Vb  = (unsigned short*)(ws + off); off += (size_t)BATCH * SEQ * 256 * 2;   // 67 MB
  unsigned short* WT  = (unsigned short*)(ws + off); off += (size_t)NQKV * DIN * 2;
  float* sumwp        = (float*)(ws + off);          off += (size_t)1024 * 256 * 4;          // 1 MB
  float* ctxp         = (float*)(ws + off);          off += (size_t)64 * 32 * 1024 * 4;      // 8.4 MB
  unsigned short* MT  = (unsigned short*)(ws + off); off += (size_t)BATCH * 65536 * 2;

  k_wt<<<(NQKV * DIN) / 256, 256, 0, stream>>>(Wqkv, WT);
  k_gemm<<<1024, 256, 0, stream>>>(x, WT, Q, Wb, Vb, sumwp);
  k_ctx<<<512, 256, 0, stream>>>(Wb, Vb, ctxp);
  k_build_m<<<64, 256, 0, stream>>>(ctxp, sumwp, Wout, MT);
  k_out<<<2048, 256, 0, stream>>>(Q, MT, gamma, out);
}

// Round 8
// 192.804 us; speedup vs baseline: 1.6063x; 1.1890x over previous
//
#include <hip/hip_runtime.h>
#include <hip/hip_bf16.h>

typedef __attribute__((ext_vector_type(8))) short short8;
typedef __attribute__((ext_vector_type(4))) float f32x4;

constexpr int SEQ = 16384, BATCH = 8, DIN = 256, NQKV = 768;
constexpr float SCALE = 0.17677669529663687f; // 32^-0.5
constexpr float EPS = 1e-5f;

__device__ __forceinline__ unsigned short f2bf(float f){
  __hip_bfloat16 h = __float2bfloat16(f);
  unsigned short u; __builtin_memcpy(&u, &h, 2); return u;
}
__device__ __forceinline__ float bf2f(unsigned short h){
  return __uint_as_float(((unsigned int)h) << 16);
}
__device__ __forceinline__ void gload_lds16(const void* g, void* l){
  __builtin_amdgcn_global_load_lds(
    (const __attribute__((address_space(1))) unsigned int*)g,
    (__attribute__((address_space(3))) unsigned int*)l, 16, 0, 0);
}

// ---- K0: Wqkv [256 x 768] fp32 -> WT [768 x 256] bf16 (transposed) ----
__global__ void k_wt(const float* __restrict__ W, unsigned short* __restrict__ WT){
  int id = blockIdx.x * 256 + threadIdx.x;
  int k = id / NQKV, n = id % NQKV;
  WT[n * DIN + k] = f2bf(W[id]);
}

// ---- K1: fused qkv GEMM + q-softmax + k-exp + in-kernel ctx Gram ----
// 1024 blocks x 256 thr (4 waves). A in regs (128 rows/block), 24 panels of
// 32 cols (K0 V0 K1 V1 .. K7 V7 Q0..Q7), dbuf 2x16KB swizzled LDS via
// global_load_lds, 1 syncthreads/panel (+1 after each ctx phase).
// LDS 50 KB -> 3 blocks/CU.
__global__ __launch_bounds__(256, 3) void k_qkv(const float* __restrict__ X,
                                                const unsigned short* __restrict__ WT,
                                                unsigned short* __restrict__ Q,
                                                float* __restrict__ ctxp,
                                                float* __restrict__ sumwp){
  __shared__ unsigned short Bs[2][32 * 256];   // 16 KB each, swizzle byte^=((row&7)<<4)
  __shared__ unsigned short WVs[2][32][136];   // w^T / v^T, 17.4 KB
  __shared__ float sumLds[256];
  const int blk = blockIdx.x;
  const size_t m0 = (size_t)blk * 128;
  const int tid = threadIdx.x, wave = tid >> 6, lane = tid & 63;
  const int lg = lane >> 4, li = lane & 15;
  sumLds[tid] = 0.f;

  auto panelN0 = [](int p){
    return (p < 16) ? (((p & 1) ? 512 : 256) + (p >> 1) * 32) : (p - 16) * 32;
  };
  auto stageB = [&](int buf, int n0){
    #pragma unroll
    for (int it = 0; it < 4; it++){
      int L = (it * 256 + tid) * 16;
      int G = L ^ (((L >> 9) & 7) << 4);       // pre-swizzled source (rule 21)
      gload_lds16((const char*)WT + (size_t)(n0 + (L >> 9)) * 512 + (G & 511),
                  (char*)Bs[buf] + L);
    }
  };

  // prologue: stage panel 0; A fragments fp32->bf16 in regs (32 VGPR)
  stageB(0, panelN0(0));
  short8 afrag[2][8];
  #pragma unroll
  for (int rt = 0; rt < 2; rt++){
    const float* xr = X + (m0 + wave * 32 + rt * 16 + li) * 256 + lg * 8;
    #pragma unroll
    for (int ks = 0; ks < 8; ks++){
      float4 f0 = *reinterpret_cast<const float4*>(xr + ks * 32);
      float4 f1 = *reinterpret_cast<const float4*>(xr + ks * 32 + 4);
      short8 a;
      a[0] = f2bf(f0.x); a[1] = f2bf(f0.y); a[2] = f2bf(f0.z); a[3] = f2bf(f0.w);
      a[4] = f2bf(f1.x); a[5] = f2bf(f1.y); a[6] = f2bf(f1.z); a[7] = f2bf(f1.w);
      afrag[rt][ks] = a;
    }
  }
  __syncthreads();

  const f32x4 zf = {0.f, 0.f, 0.f, 0.f};
  int buf = 0;
  #pragma unroll 1
  for (int p = 0; p < 24; ++p){
    if (p < 23) stageB(buf ^ 1, panelN0(p + 1));
    // panel matmul: 32 MFMAs/wave
    f32x4 acc[2][2];
    acc[0][0] = zf; acc[0][1] = zf; acc[1][0] = zf; acc[1][1] = zf;
    #pragma unroll
    for (int ks = 0; ks < 8; ks++)
      #pragma unroll
      for (int j = 0; j < 2; j++){
        int nl = j * 16 + li;
        int L = nl * 512 + (ks * 32 + lg * 8) * 2;
        short8 bb = *reinterpret_cast<const short8*>((const char*)Bs[buf] + (L ^ ((nl & 7) << 4)));
        acc[0][j] = __builtin_amdgcn_mfma_f32_16x16x32_bf16(afrag[0][ks], bb, acc[0][j], 0, 0, 0);
        acc[1][j] = __builtin_amdgcn_mfma_f32_16x16x32_bf16(afrag[1][ks], bb, acc[1][j], 0, 0, 0);
      }
    // fused epilogue
    if (p < 16){
      int h = p >> 1;
      if (!(p & 1)){
        // K panel (head h): w = exp(k) (k ~ N(0,1), safe), stage w^T + col sums
        #pragma unroll
        for (int j = 0; j < 2; j++){
          float cs = 0.f;
          #pragma unroll
          for (int rt = 0; rt < 2; rt++){
            unsigned short h0 = f2bf(__expf(acc[rt][j][0]));
            unsigned short h1 = f2bf(__expf(acc[rt][j][1]));
            unsigned short h2 = f2bf(__expf(acc[rt][j][2]));
            unsigned short h3 = f2bf(__expf(acc[rt][j][3]));
            cs += bf2f(h0) + bf2f(h1) + bf2f(h2) + bf2f(h3);
            ushort4 pk; pk.x = h0; pk.y = h1; pk.z = h2; pk.w = h3;
            *reinterpret_cast<ushort4*>(&WVs[0][j * 16 + li][wave * 32 + rt * 16 + lg * 4]) = pk;
          }
          cs += __shfl_xor(cs, 16); cs += __shfl_xor(cs, 32);
          if (lane < 16) atomicAdd(&sumLds[h * 32 + j * 16 + li], cs);
        }
      } else {
        // V panel: stage v^T
        #pragma unroll
        for (int j = 0; j < 2; j++)
          #pragma unroll
          for (int rt = 0; rt < 2; rt++){
            ushort4 pk;
            pk.x = f2bf(acc[rt][j][0]); pk.y = f2bf(acc[rt][j][1]);
            pk.z = f2bf(acc[rt][j][2]); pk.w = f2bf(acc[rt][j][3]);
            *reinterpret_cast<ushort4*>(&WVs[1][j * 16 + li][wave * 32 + rt * 16 + lg * 4]) = pk;
          }
      }
    } else {
      // Q panel (head ph): fp32 softmax over 32 cols, *SCALE, direct store
      int ph = p - 16;
      #pragma unroll
      for (int rt = 0; rt < 2; rt++){
        unsigned short* qp = Q + (m0 + wave * 32 + rt * 16 + lg * 4) * 256 + ph * 32;
        #pragma unroll
        for (int r = 0; r < 4; r++){
          float a0 = acc[rt][0][r], a1 = acc[rt][1][r];
          float mx = fmaxf(a0, a1);
          #pragma unroll
          for (int mm = 1; mm < 16; mm <<= 1) mx = fmaxf(mx, __shfl_xor(mx, mm));
          float e0 = __expf(a0 - mx), e1 = __expf(a1 - mx);
          float s = e0 + e1;
          #pragma unroll
          for (int mm = 1; mm < 16; mm <<= 1) s += __shfl_xor(s, mm);
          float iv = SCALE / s;
          unsigned short* rp = qp + r * 256;
          rp[li]      = f2bf(e0 * iv);
          rp[16 + li] = f2bf(e1 * iv);
        }
      }
    }
    __syncthreads();   // drains stage(p+1) + all waves done with Bs[buf] & WVs writes
    if (p < 16 && (p & 1)){
      // ctx[h][d][e] += w^T[d][t] * v^T[e][t] over this block's 128 tokens
      int h = p >> 1;
      int dh = wave >> 1, eh = wave & 1;
      f32x4 c = zf;
      #pragma unroll
      for (int ks = 0; ks < 4; ks++){
        short8 aw = *reinterpret_cast<const short8*>(&WVs[0][dh * 16 + li][ks * 32 + lg * 8]);
        short8 bv = *reinterpret_cast<const short8*>(&WVs[1][eh * 16 + li][ks * 32 + lg * 8]);
        c = __builtin_amdgcn_mfma_f32_16x16x32_bf16(aw, bv, c, 0, 0, 0);
      }
      float* cp = ctxp + ((size_t)blk * 8 + h) * 1024;
      #pragma unroll
      for (int r = 0; r < 4; r++)
        cp[(dh * 16 + lg * 4 + r) * 32 + eh * 16 + li] = c[r];
      __syncthreads();   // protect WVs from next K panel's overwrite
    }
    buf ^= 1;
  }
  sumwp[(size_t)blk * 256 + tid] = sumLds[tid];
}

// ---- K2a: reduce ctx partials 128 -> 16 chunks (full-chip parallel) ----
__global__ __launch_bounds__(256) void k_red1(const float* __restrict__ ctxp,
                                              const float* __restrict__ sumwp,
                                              float* __restrict__ ctxr,
                                              float* __restrict__ sumr){
  int bid = blockIdx.x;              // ((b*8+h)*16+s)
  int s = bid & 15, bh = bid >> 4;
  int b = bh >> 3, h = bh & 7;
  int t = threadIdx.x;
  float a[4] = {0.f, 0.f, 0.f, 0.f};
  #pragma unroll
  for (int k = 0; k < 8; k++){
    const float* cp = ctxp + ((size_t)(b * 128 + s * 8 + k) * 8 + h) * 1024;
    #pragma unroll
    for (int q = 0; q < 4; q++) a[q] += cp[q * 256 + t];
  }
  float* orow = ctxr + (size_t)bid * 1024;
  #pragma unroll
  for (int q = 0; q < 4; q++) orow[q * 256 + t] = a[q];
  if (t < 32){
    float sw = 0.f;
    #pragma unroll
    for (int k = 0; k < 8; k++)
      sw += sumwp[(size_t)(b * 128 + s * 8 + k) * 256 + h * 32 + t];
    sumr[(size_t)bid * 32 + t] = sw;
  }
}

// ---- K2b: final reduce, /sumw, fold Wout -> MT[b][j][hd] bf16 ----
__global__ __launch_bounds__(256) void k_build_m(const float* __restrict__ ctxr,
                                                 const float* __restrict__ sumr,
                                                 const float* __restrict__ Wout,
                                                 unsigned short* __restrict__ MT){
  __shared__ float ctxs[32][33];
  __shared__ float swb[32];
  int b = blockIdx.x >> 3, h = blockIdx.x & 7;
  int bh16 = (b * 8 + h) * 16;
  int t = threadIdx.x;
  int e = t & 31, dq = t >> 5;
  float a0 = 0.f, a1 = 0.f, a2 = 0.f, a3 = 0.f;
  #pragma unroll
  for (int s = 0; s < 16; s++){
    const float* cp = ctxr + (size_t)(bh16 + s) * 1024;
    a0 += cp[dq * 32 + e];         a1 += cp[(dq + 8) * 32 + e];
    a2 += cp[(dq + 16) * 32 + e];  a3 += cp[(dq + 24) * 32 + e];
  }
  if (t < 32){
    float sw = 0.f;
    #pragma unroll
    for (int s = 0; s < 16; s++) sw += sumr[(size_t)(bh16 + s) * 32 + t];
    swb[t] = sw;
  }
  __syncthreads();
  ctxs[dq][e]      = a0 / swb[dq];
  ctxs[dq + 8][e]  = a1 / swb[dq + 8];
  ctxs[dq + 16][e] = a2 / swb[dq + 16];
  ctxs[dq + 24][e] = a3 / swb[dq + 24];
  __syncthreads();
  float s[32];
  #pragma unroll
  for (int d = 0; d < 32; d++) s[d] = 0.f;
  for (int ee = 0; ee < 32; ee++){
    float wv = Wout[(size_t)(h * 32 + ee) * 256 + t];
    #pragma unroll
    for (int d = 0; d < 32; d++) s[d] += ctxs[d][ee] * wv;
  }
  unsigned short* mp = MT + (size_t)b * 65536 + (size_t)t * 256 + h * 32;
  #pragma unroll
  for (int d8 = 0; d8 < 4; d8++){
    short8 pk;
    #pragma unroll
    for (int q = 0; q < 8; q++) pk[q] = (short)f2bf(s[d8 * 8 + q]);
    *reinterpret_cast<short8*>(mp + d8 * 8) = pk;
  }
}

// ---- K3: out = LN( qs @ MT^T ) * gamma ; 2048 blocks x 256 thr, 64 rows/block ----
__global__ __launch_bounds__(256, 4) void k_out(const unsigned short* __restrict__ Qm,
                                                const unsigned short* __restrict__ MT,
                                                const float* __restrict__ gamma,
                                                float* __restrict__ out){
  __shared__ unsigned short Bs[64 * 256];  // 32 KB swizzled
  const int blk = blockIdx.x;
  const int b = blk >> 8;
  const size_t m0 = (size_t)blk * 64;
  const int tid = threadIdx.x, wave = tid >> 6, lane = tid & 63;
  const int lg = lane >> 4, li = lane & 15;

  short8 afrag[8];
  {
    const unsigned short* qr = Qm + (m0 + wave * 16 + li) * 256 + lg * 8;
    #pragma unroll
    for (int ks = 0; ks < 8; ks++)
      afrag[ks] = *reinterpret_cast<const short8*>(qr + ks * 32);
  }
  const char* mtb = (const char*)MT + (size_t)b * 131072;
  f32x4 acc[4][4];
  const f32x4 zf = {0.f, 0.f, 0.f, 0.f};
  #pragma unroll
  for (int jb = 0; jb < 4; jb++)
    #pragma unroll
    for (int j = 0; j < 4; j++) acc[jb][j] = zf;

  #pragma unroll
  for (int jb = 0; jb < 4; jb++){
    if (jb) __syncthreads();
    #pragma unroll
    for (int rr = 0; rr < 8; rr++){
      int L = rr * 4096 + tid * 16;
      int G = L ^ (((L >> 9) & 7) << 4);   // pre-swizzled source (rule 21)
      gload_lds16(mtb + (size_t)jb * 32768 + G, (char*)Bs + L);
    }
    __syncthreads();
    #pragma unroll
    for (int ks = 0; ks < 8; ks++)
      #pragma unroll
      for (int j = 0; j < 4; j++){
        int n = j * 16 + li;
        int L = n * 512 + (ks * 32 + lg * 8) * 2;
        short8 bb = *reinterpret_cast<const short8*>((const char*)Bs + (L ^ ((n & 7) << 4)));
        acc[jb][j] = __builtin_amdgcn_mfma_f32_16x16x32_bf16(afrag[ks], bb, acc[jb][j], 0, 0, 0);
      }
  }

  float gam[16];
  #pragma unroll
  for (int jb = 0; jb < 4; jb++)
    #pragma unroll
    for (int j = 0; j < 4; j++) gam[jb * 4 + j] = gamma[jb * 64 + j * 16 + li];
  #pragma unroll
  for (int r = 0; r < 4; r++){
    float s = 0.f, qq = 0.f;
    #pragma unroll
    for (int jb = 0; jb < 4; jb++)
      #pragma unroll
      for (int j = 0; j < 4; j++){ float v = acc[jb][j][r]; s += v; qq += v * v; }
    #pragma unroll
    for (int mm = 1; mm < 16; mm <<= 1){ s += __shfl_xor(s, mm); qq += __shfl_xor(qq, mm); }
    float mu = s * (1.f / 256.f);
    float var = qq * (1.f / 256.f) - mu * mu;
    float inv = rsqrtf(var + EPS);
    float* op = out + (m0 + wave * 16 + lg * 4 + r) * 256;
    #pragma unroll
    for (int jb = 0; jb < 4; jb++)
      #pragma unroll
      for (int j = 0; j < 4; j++)
        op[jb * 64 + j * 16 + li] = (acc[jb][j][r] - mu) * inv * gam[jb * 4 + j];
  }
}

extern "C" void kernel_launch(void* const* d_in, const int* in_sizes, int n_in,
                              void* d_out, int out_size, void* d_ws, size_t ws_size,
                              hipStream_t stream){
  const float* x     = (const float*)d_in[0];
  const float* Wqkv  = (const float*)d_in[1];
  const float* Wout  = (const float*)d_in[2];
  const float* gamma = (const float*)d_in[3];
  float* out = (float*)d_out;

  char* ws = (char*)d_ws;
  size_t off = 0;
  unsigned short* Q   = (unsigned short*)(ws + off); off += (size_t)BATCH * SEQ * 256 * 2;   // 67 MB
  unsigned short* WT  = (unsigned short*)(ws + off); off += (size_t)NQKV * DIN * 2;
  float* ctxp         = (float*)(ws + off);          off += (size_t)1024 * 8 * 1024 * 4;     // 33.6 MB
  float* sumwp        = (float*)(ws + off);          off += (size_t)1024 * 256 * 4;          // 1 MB
  float* ctxr         = (float*)(ws + off);          off += (size_t)1024 * 1024 * 4;         // 4.2 MB
  float* sumr         = (float*)(ws + off);          off += (size_t)1024 * 32 * 4;
  unsigned short* MT  = (unsigned short*)(ws + off); off += (size_t)BATCH * 65536 * 2;

  k_wt<<<(NQKV * DIN) / 256, 256, 0, stream>>>(Wqkv, WT);
  k_qkv<<<1024, 256, 0, stream>>>(x, WT, Q, ctxp, sumwp);
  k_red1<<<1024, 256, 0, stream>>>(ctxp, sumwp, ctxr, sumr);
  k_build_m<<<64, 256, 0, stream>>>(ctxr, sumr, Wout, MT);
  k_out<<<2048, 256, 0, stream>>>(Q, MT, gamma, out);
}